// Round 6
// baseline (113.245 us; speedup 1.0000x reference)
//
#include <hip/hip_runtime.h>
#include <hip/hip_bf16.h>

// Problem constants (match reference)
#define N_OUT_ROWS 250000
#define TILES 15625      // 16-row output tiles
#define NBLK 512         // 2 blocks/CU (66KB LDS each)
#define WPB 4            // waves per block
#define NWAVES (NBLK * WPB)  // 2048
#define BN_EPS 1e-5f

#define SB() __builtin_amdgcn_sched_barrier(0)

typedef __attribute__((ext_vector_type(8))) short bf16x8;
typedef __attribute__((ext_vector_type(8))) unsigned short u16x8;
typedef __attribute__((ext_vector_type(4))) float f32x4;

static __device__ __forceinline__ unsigned short f2bf(float f) {
  union { float f; unsigned u; } v; v.f = f;
  unsigned r = v.u + 0x7FFFu + ((v.u >> 16) & 1u);
  return (unsigned short)(r >> 16);
}
static __device__ __forceinline__ float bf2f(unsigned short s) {
  union { unsigned u; float f; } v; v.u = ((unsigned)s) << 16;
  return v.f;
}

// Fire-and-forget 16B gather into LDS (per-lane global src, linear LDS dest).
#define GLOAD_LDS16(gsrc, ldst)                                                \
  __builtin_amdgcn_global_load_lds(                                            \
      (const __attribute__((address_space(1))) unsigned int*)(gsrc),           \
      (__attribute__((address_space(3))) unsigned int*)(ldst), 16, 0, 0)

// Prep: weights f32 -> bf16 fragment layout in d_ws, zero stats.
__global__ void k_prep(const float* __restrict__ w,
                       unsigned short* __restrict__ bfrag,
                       float* __restrict__ stats) {
  const int i = blockIdx.x * 256 + threadIdx.x;  // 0..2047
  if (i < 128) stats[i] = 0.f;
  const int f = i >> 6, l = i & 63;
  const int kt = f >> 2, ct = f & 3, rr = l & 15, gg = l >> 4;
  u16x8 o;
  #pragma unroll
  for (int j = 0; j < 8; ++j)
    o[j] = f2bf(w[(kt * 32 + gg * 8 + j) * 64 + ct * 16 + rr]);
  *reinterpret_cast<u16x8*>(bfrag + i * 8) = o;
}

// Fused gather + bf16-MFMA GEMM + BN partials. Round-3 proven structure
// (2 blocks/CU, vmcnt(0)-per-tile: count-independent, race-immune; 8 waves/CU
// TLP covers gather latency -- measured better than 1-tile-deep counted
// pipeline at half occupancy, r5 A/B). BF16OUT: store pre-BN intermediate as
// bf16 (halves write traffic; bn re-read is L3-hot). We are ~87% of the
// 6.3 TB/s vector-traffic ceiling -- bytes are the lever, not latency.
template <bool BF16OUT>
__global__ __launch_bounds__(256, 2)
void k_gemm(const float* __restrict__ x, const int* __restrict__ neigh,
            const unsigned short* __restrict__ bfrag,
            float* __restrict__ outf, unsigned short* __restrict__ outb,
            float* __restrict__ stats) {
  __shared__ __align__(16) unsigned char Abuf_all[WPB][16384];  // 64 KB

  const int tid = threadIdx.x;
  const int lane = tid & 63;
  const int widx = tid >> 6;
  unsigned char* Abuf = Abuf_all[widx];

  // B fragments fully in registers (32 frags = 128 VGPR).
  bf16x8 bf[8][4];
  #pragma unroll
  for (int kt = 0; kt < 8; ++kt)
    #pragma unroll
    for (int ct = 0; ct < 4; ++ct)
      bf[kt][ct] = *reinterpret_cast<const bf16x8*>(
          bfrag + ((kt * 4 + ct) * 64 + lane) * 8);

  // Contiguous tile range per wave.
  const int gw = blockIdx.x * WPB + widx;  // 0..2047
  const int q = TILES / NWAVES;            // 7
  const int rem = TILES % NWAVES;          // 1289
  const int start = (gw < rem) ? gw * (q + 1) : rem * (q + 1) + (gw - rem) * q;
  const int cnt = q + (gw < rem ? 1 : 0);

  const int r = lane & 15;     // A row within tile / C col-within-group
  const int g4 = lane >> 4;    // k-slice group
  const int seg = lane & 7;    // 16B segment within a 128B x-row
  const int ktl = lane >> 3;   // neighbor slot for gather addressing
  const int swz = (r & 7) << 4;
  const int rdbase = (r << 10) + (g4 << 5);

  float sacc[4] = {0.f, 0.f, 0.f, 0.f};
  float qacc[4] = {0.f, 0.f, 0.f, 0.f};

  for (int k = 0; k < cnt; ++k) {
    const int t = start + k;
    const int n0 = t << 4;

    // idx: 128 ints per tile via 2 coalesced dwords + shfl distribution.
    const int* p = neigh + t * 128;
    const int ia = p[lane];
    const int ib = p[64 + lane];

    // WAR guard: previous tile's ds_reads (and idx bpermutes) retired.
    asm volatile("s_waitcnt lgkmcnt(0)" ::: "memory");
    SB();

    // 16 gathers: instr j stages output-row j's 8 neighbor rows (1KB).
    // Source segment pre-permuted (seg^(j&7)) = XOR-swizzled linear LDS
    // layout (Rule 21); read side applies the same involution.
    #pragma unroll
    for (int j = 0; j < 16; ++j) {
      const int id = __shfl((j < 8) ? ia : ib, ((j & 7) << 3) + ktl, 64);
      const float* src = x + (size_t)id * 32 + ((seg ^ (j & 7)) << 2);
      GLOAD_LDS16(src, Abuf + j * 1024);
    }

    // Drain gathers (count-independent -> immune to scheduler reordering).
    asm volatile("s_waitcnt vmcnt(0)" ::: "memory");
    SB();

    f32x4 acc[4];
    #pragma unroll
    for (int ct = 0; ct < 4; ++ct) acc[ct] = (f32x4){0.f, 0.f, 0.f, 0.f};

    #pragma unroll
    for (int kt = 0; kt < 8; ++kt) {
      const int o0 = rdbase + (kt << 7);
      const f32x4 a0 = *reinterpret_cast<const f32x4*>(Abuf + (o0 ^ swz));
      const f32x4 a1 = *reinterpret_cast<const f32x4*>(Abuf + ((o0 + 16) ^ swz));
      union { bf16x8 v; __hip_bfloat162 h[4]; } af;
      af.h[0] = __float22bfloat162_rn(make_float2(a0[0], a0[1]));
      af.h[1] = __float22bfloat162_rn(make_float2(a0[2], a0[3]));
      af.h[2] = __float22bfloat162_rn(make_float2(a1[0], a1[1]));
      af.h[3] = __float22bfloat162_rn(make_float2(a1[2], a1[3]));
      #pragma unroll
      for (int ct = 0; ct < 4; ++ct)
        acc[ct] = __builtin_amdgcn_mfma_f32_16x16x32_bf16(af.v, bf[kt][ct],
                                                          acc[ct], 0, 0, 0);
    }

    // C write: col = ct*16 + r, row = g4*4 + j; accumulate BN partials
    // (stats from unrounded f32 -- closer to reference than post-bf16).
    const int rbase = n0 + g4 * 4;
    #pragma unroll
    for (int ct = 0; ct < 4; ++ct) {
      #pragma unroll
      for (int j = 0; j < 4; ++j) {
        const int off = (rbase + j) * 64 + ct * 16 + r;
        if (BF16OUT) outb[off] = f2bf(acc[ct][j]);
        else         outf[off] = acc[ct][j];
      }
      sacc[ct] += acc[ct][0] + acc[ct][1] + acc[ct][2] + acc[ct][3];
      qacc[ct] += acc[ct][0] * acc[ct][0] + acc[ct][1] * acc[ct][1] +
                  acc[ct][2] * acc[ct][2] + acc[ct][3] * acc[ct][3];
    }
  }

  // Per-wave BN reduction: fold g4 groups, 8 atomics per wave.
  #pragma unroll
  for (int ct = 0; ct < 4; ++ct) {
    sacc[ct] += __shfl_xor(sacc[ct], 16);
    qacc[ct] += __shfl_xor(qacc[ct], 16);
    sacc[ct] += __shfl_xor(sacc[ct], 32);
    qacc[ct] += __shfl_xor(qacc[ct], 32);
  }
  if (lane < 16) {
    #pragma unroll
    for (int ct = 0; ct < 4; ++ct) {
      atomicAdd(&stats[ct * 16 + lane], sacc[ct]);
      atomicAdd(&stats[64 + ct * 16 + lane], qacc[ct]);
    }
  }
}

// Finalize BN: y = (v - mean) * rsqrt(var+eps) * gamma + beta.
// BF16IN: read bf16 intermediate (L3-hot), write f32 output.
template <bool BF16IN>
__global__ __launch_bounds__(256)
void k_bn(float* __restrict__ out, const unsigned short* __restrict__ inb,
          const float* __restrict__ stats, const float* __restrict__ gamma,
          const float* __restrict__ beta) {
  __shared__ float sc[64], bs[64];
  if (threadIdx.x < 64) {
    const int d = threadIdx.x;
    const float inv = 1.0f / (float)N_OUT_ROWS;
    const float mean = stats[d] * inv;
    const float var = stats[64 + d] * inv - mean * mean;
    const float rstd = rsqrtf(var + BN_EPS);
    const float scale = rstd * gamma[d];
    sc[d] = scale;
    bs[d] = beta[d] - mean * scale;
  }
  __syncthreads();

  if (BF16IN) {
    const int total8 = N_OUT_ROWS * 64 / 8;  // 2M chunks of 8 elems
    for (int i = blockIdx.x * blockDim.x + threadIdx.x; i < total8;
         i += gridDim.x * blockDim.x) {
      const int d0 = (i & 7) << 3;  // 8 chunks per 64-ch row
      const u16x8 v = *reinterpret_cast<const u16x8*>(inb + i * 8);
      float4 o0, o1;
      o0.x = bf2f(v[0]) * sc[d0 + 0] + bs[d0 + 0];
      o0.y = bf2f(v[1]) * sc[d0 + 1] + bs[d0 + 1];
      o0.z = bf2f(v[2]) * sc[d0 + 2] + bs[d0 + 2];
      o0.w = bf2f(v[3]) * sc[d0 + 3] + bs[d0 + 3];
      o1.x = bf2f(v[4]) * sc[d0 + 4] + bs[d0 + 4];
      o1.y = bf2f(v[5]) * sc[d0 + 5] + bs[d0 + 5];
      o1.z = bf2f(v[6]) * sc[d0 + 6] + bs[d0 + 6];
      o1.w = bf2f(v[7]) * sc[d0 + 7] + bs[d0 + 7];
      reinterpret_cast<float4*>(out)[i * 2] = o0;
      reinterpret_cast<float4*>(out)[i * 2 + 1] = o1;
    }
  } else {
    const int total4 = N_OUT_ROWS * 64 / 4;
    float4* o4 = reinterpret_cast<float4*>(out);
    for (int i = blockIdx.x * blockDim.x + threadIdx.x; i < total4;
         i += gridDim.x * blockDim.x) {
      const int d0 = (i & 15) << 2;
      float4 v = o4[i];
      v.x = v.x * sc[d0]     + bs[d0];
      v.y = v.y * sc[d0 + 1] + bs[d0 + 1];
      v.z = v.z * sc[d0 + 2] + bs[d0 + 2];
      v.w = v.w * sc[d0 + 3] + bs[d0 + 3];
      o4[i] = v;
    }
  }
}

extern "C" void kernel_launch(void* const* d_in, const int* in_sizes, int n_in,
                              void* d_out, int out_size, void* d_ws, size_t ws_size,
                              hipStream_t stream) {
  const float* x     = (const float*)d_in[0];
  const int*   neigh = (const int*)d_in[1];
  const float* w     = (const float*)d_in[2];
  const float* gamma = (const float*)d_in[3];
  const float* beta  = (const float*)d_in[4];
  float* out = (float*)d_out;

  float* stats = (float*)d_ws;                                    // 512 B
  unsigned short* bfrag = (unsigned short*)((char*)d_ws + 1024);  // 32 KB
  unsigned short* obf = (unsigned short*)((char*)d_ws + 65536);   // 32 MB

  const bool bf16path =
      ws_size >= (size_t)65536 + (size_t)N_OUT_ROWS * 64 * 2;

  k_prep<<<8, 256, 0, stream>>>(w, bfrag, stats);
  if (bf16path) {
    k_gemm<true><<<NBLK, 256, 0, stream>>>(x, neigh, bfrag, nullptr, obf, stats);
    k_bn<true><<<2048, 256, 0, stream>>>(out, obf, stats, gamma, beta);
  } else {
    k_gemm<false><<<NBLK, 256, 0, stream>>>(x, neigh, bfrag, out, nullptr, stats);
    k_bn<false><<<2048, 256, 0, stream>>>(out, nullptr, stats, gamma, beta);
  }
}

// Round 7
// 80.367 us; speedup vs baseline: 1.4091x; 1.4091x over previous
//
#include <hip/hip_runtime.h>
#include <hip/hip_bf16.h>

// Problem constants (match reference)
#define N_OUT_ROWS 250000
#define TILES 15625      // 16-row output tiles
#define NBLK 512         // 2 blocks/CU (66KB LDS each)
#define WPB 4            // waves per block
#define NWAVES (NBLK * WPB)  // 2048
#define BN_EPS 1e-5f

typedef __attribute__((ext_vector_type(8))) short bf16x8;
typedef __attribute__((ext_vector_type(8))) unsigned short u16x8;
typedef __attribute__((ext_vector_type(4))) float f32x4;

static __device__ __forceinline__ unsigned short f2bf(float f) {
  union { float f; unsigned u; } v; v.f = f;
  unsigned r = v.u + 0x7FFFu + ((v.u >> 16) & 1u);
  return (unsigned short)(r >> 16);
}
static __device__ __forceinline__ float bf2f(unsigned short s) {
  union { unsigned u; float f; } v; v.u = ((unsigned)s) << 16;
  return v.f;
}

// Fire-and-forget 16B gather into LDS (per-lane global src, linear LDS dest).
#define GLOAD_LDS16(gsrc, ldst)                                                \
  __builtin_amdgcn_global_load_lds(                                            \
      (const __attribute__((address_space(1))) unsigned int*)(gsrc),           \
      (__attribute__((address_space(3))) unsigned int*)(ldst), 16, 0, 0)

// Prep: weights f32 -> bf16 fragment layout in d_ws, zero stats.
__global__ void k_prep(const float* __restrict__ w,
                       unsigned short* __restrict__ bfrag,
                       float* __restrict__ stats) {
  const int i = blockIdx.x * 256 + threadIdx.x;  // 0..2047
  if (i < 128) stats[i] = 0.f;
  const int f = i >> 6, l = i & 63;
  const int kt = f >> 2, ct = f & 3, rr = l & 15, gg = l >> 4;
  u16x8 o;
  #pragma unroll
  for (int j = 0; j < 8; ++j)
    o[j] = f2bf(w[(kt * 32 + gg * 8 + j) * 64 + ct * 16 + rr]);
  *reinterpret_cast<u16x8*>(bfrag + i * 8) = o;
}

// Fused gather + bf16-MFMA GEMM + BN partials. EXACT round-3 structure
// (measured 85.5us): direct per-lane idx loads so all 16 gather addresses are
// in VGPRs and the global_load_lds burst issues BACK-TO-BACK (max queue
// depth; r5/r6 showed shfl-distributed idx smears the burst and loses ~15-25%
// in this queueing-bound regime); vmcnt(0) per tile (count-independent,
// race-immune); block-level stats (LDS + barrier, 128 atomics/block).
// ONLY delta vs r3: optional bf16 intermediate store (halves write bytes).
template <bool BF16OUT>
__global__ __launch_bounds__(256, 2)
void k_gemm(const float* __restrict__ x, const int* __restrict__ neigh,
            const unsigned short* __restrict__ bfrag,
            float* __restrict__ outf, unsigned short* __restrict__ outb,
            float* __restrict__ stats) {
  __shared__ __align__(16) unsigned char Abuf_all[WPB][16384];  // 64 KB
  __shared__ float wpart[WPB][128];

  const int tid = threadIdx.x;
  const int lane = tid & 63;
  const int widx = tid >> 6;
  unsigned char* Abuf = Abuf_all[widx];

  // B fragments fully in registers (32 frags = 128 VGPR).
  bf16x8 bf[8][4];
  #pragma unroll
  for (int kt = 0; kt < 8; ++kt)
    #pragma unroll
    for (int ct = 0; ct < 4; ++ct)
      bf[kt][ct] = *reinterpret_cast<const bf16x8*>(
          bfrag + ((kt * 4 + ct) * 64 + lane) * 8);

  // Contiguous tile range per wave (sequential neigh reads).
  const int gw = blockIdx.x * WPB + widx;  // 0..2047
  const int q = TILES / NWAVES;            // 7
  const int rem = TILES % NWAVES;          // 1289
  const int start = (gw < rem) ? gw * (q + 1) : rem * (q + 1) + (gw - rem) * q;
  const int cnt = q + (gw < rem ? 1 : 0);

  const int r = lane & 15;     // A row within tile / C col-within-group
  const int g4 = lane >> 4;    // k-slice group
  const int seg = lane & 7;    // 16B segment within a 128B x-row
  const int ktl = lane >> 3;   // which neighbor this lane fetches
  const int swz = (r & 7) << 4;
  const int rdbase = (r << 10) + (g4 << 5);

  float sacc[4] = {0.f, 0.f, 0.f, 0.f};
  float qacc[4] = {0.f, 0.f, 0.f, 0.f};

  for (int k = 0; k < cnt; ++k) {
    const int t = start + k;
    const int n0 = t << 4;

    // Direct idx loads: addresses land in VGPRs before the gather burst.
    int idxv[16];
    #pragma unroll
    for (int m = 0; m < 16; ++m)
      idxv[m] = neigh[(n0 + m) * 8 + ktl];

    // WAR guard: previous tile's ds_reads fully retired before overwriting.
    asm volatile("s_waitcnt lgkmcnt(0)" ::: "memory");
    __builtin_amdgcn_sched_barrier(0);

    // 16 gathers back-to-back: instr j stages output-row j's 8 neighbor rows.
    // Source segment pre-permuted (seg^(j&7)) = XOR-swizzled linear LDS
    // layout (Rule 21); read side applies the same involution.
    #pragma unroll
    for (int j = 0; j < 16; ++j) {
      const float* src = x + (size_t)idxv[j] * 32 + ((seg ^ (j & 7)) << 2);
      GLOAD_LDS16(src, Abuf + j * 1024);
    }

    // Drain gathers (count-independent -> immune to scheduler reordering).
    asm volatile("s_waitcnt vmcnt(0)" ::: "memory");
    __builtin_amdgcn_sched_barrier(0);

    f32x4 acc[4];
    #pragma unroll
    for (int ct = 0; ct < 4; ++ct) acc[ct] = (f32x4){0.f, 0.f, 0.f, 0.f};

    #pragma unroll
    for (int kt = 0; kt < 8; ++kt) {
      const int o0 = rdbase + (kt << 7);
      const f32x4 a0 = *reinterpret_cast<const f32x4*>(Abuf + (o0 ^ swz));
      const f32x4 a1 = *reinterpret_cast<const f32x4*>(Abuf + ((o0 + 16) ^ swz));
      union { bf16x8 v; __hip_bfloat162 h[4]; } af;
      af.h[0] = __float22bfloat162_rn(make_float2(a0[0], a0[1]));
      af.h[1] = __float22bfloat162_rn(make_float2(a0[2], a0[3]));
      af.h[2] = __float22bfloat162_rn(make_float2(a1[0], a1[1]));
      af.h[3] = __float22bfloat162_rn(make_float2(a1[2], a1[3]));
      #pragma unroll
      for (int ct = 0; ct < 4; ++ct)
        acc[ct] = __builtin_amdgcn_mfma_f32_16x16x32_bf16(af.v, bf[kt][ct],
                                                          acc[ct], 0, 0, 0);
    }

    // C write: col = ct*16 + r, row = g4*4 + j; BN partials from unrounded f32.
    const int rbase = n0 + g4 * 4;
    #pragma unroll
    for (int ct = 0; ct < 4; ++ct) {
      #pragma unroll
      for (int j = 0; j < 4; ++j) {
        const int off = (rbase + j) * 64 + ct * 16 + r;
        if (BF16OUT) outb[off] = f2bf(acc[ct][j]);
        else         outf[off] = acc[ct][j];
      }
      sacc[ct] += acc[ct][0] + acc[ct][1] + acc[ct][2] + acc[ct][3];
      qacc[ct] += acc[ct][0] * acc[ct][0] + acc[ct][1] * acc[ct][1] +
                  acc[ct][2] * acc[ct][2] + acc[ct][3] * acc[ct][3];
    }
  }

  // Block-level BN stats reduction (r3-proven): shuffle across g4 groups,
  // LDS combine across waves, 128 atomics per block.
  #pragma unroll
  for (int ct = 0; ct < 4; ++ct) {
    sacc[ct] += __shfl_xor(sacc[ct], 16);
    qacc[ct] += __shfl_xor(qacc[ct], 16);
    sacc[ct] += __shfl_xor(sacc[ct], 32);
    qacc[ct] += __shfl_xor(qacc[ct], 32);
  }
  if (lane < 16) {
    #pragma unroll
    for (int ct = 0; ct < 4; ++ct) {
      wpart[widx][ct * 16 + lane] = sacc[ct];
      wpart[widx][64 + ct * 16 + lane] = qacc[ct];
    }
  }
  __syncthreads();
  if (tid < 128) {
    atomicAdd(&stats[tid], wpart[0][tid] + wpart[1][tid] +
                           wpart[2][tid] + wpart[3][tid]);
  }
}

// Finalize BN: y = (v - mean) * rsqrt(var+eps) * gamma + beta.
// BF16IN: read bf16 intermediate (L3-hot), write f32 output.
template <bool BF16IN>
__global__ __launch_bounds__(256)
void k_bn(float* __restrict__ out, const unsigned short* __restrict__ inb,
          const float* __restrict__ stats, const float* __restrict__ gamma,
          const float* __restrict__ beta) {
  __shared__ float sc[64], bs[64];
  if (threadIdx.x < 64) {
    const int d = threadIdx.x;
    const float inv = 1.0f / (float)N_OUT_ROWS;
    const float mean = stats[d] * inv;
    const float var = stats[64 + d] * inv - mean * mean;
    const float rstd = rsqrtf(var + BN_EPS);
    const float scale = rstd * gamma[d];
    sc[d] = scale;
    bs[d] = beta[d] - mean * scale;
  }
  __syncthreads();

  if (BF16IN) {
    const int total8 = N_OUT_ROWS * 64 / 8;  // 2M chunks of 8 elems
    for (int i = blockIdx.x * blockDim.x + threadIdx.x; i < total8;
         i += gridDim.x * blockDim.x) {
      const int d0 = (i & 7) << 3;  // 8 chunks per 64-ch row
      const u16x8 v = *reinterpret_cast<const u16x8*>(inb + i * 8);
      float4 o0, o1;
      o0.x = bf2f(v[0]) * sc[d0 + 0] + bs[d0 + 0];
      o0.y = bf2f(v[1]) * sc[d0 + 1] + bs[d0 + 1];
      o0.z = bf2f(v[2]) * sc[d0 + 2] + bs[d0 + 2];
      o0.w = bf2f(v[3]) * sc[d0 + 3] + bs[d0 + 3];
      o1.x = bf2f(v[4]) * sc[d0 + 4] + bs[d0 + 4];
      o1.y = bf2f(v[5]) * sc[d0 + 5] + bs[d0 + 5];
      o1.z = bf2f(v[6]) * sc[d0 + 6] + bs[d0 + 6];
      o1.w = bf2f(v[7]) * sc[d0 + 7] + bs[d0 + 7];
      reinterpret_cast<float4*>(out)[i * 2] = o0;
      reinterpret_cast<float4*>(out)[i * 2 + 1] = o1;
    }
  } else {
    const int total4 = N_OUT_ROWS * 64 / 4;
    float4* o4 = reinterpret_cast<float4*>(out);
    for (int i = blockIdx.x * blockDim.x + threadIdx.x; i < total4;
         i += gridDim.x * blockDim.x) {
      const int d0 = (i & 15) << 2;
      float4 v = o4[i];
      v.x = v.x * sc[d0]     + bs[d0];
      v.y = v.y * sc[d0 + 1] + bs[d0 + 1];
      v.z = v.z * sc[d0 + 2] + bs[d0 + 2];
      v.w = v.w * sc[d0 + 3] + bs[d0 + 3];
      o4[i] = v;
    }
  }
}

extern "C" void kernel_launch(void* const* d_in, const int* in_sizes, int n_in,
                              void* d_out, int out_size, void* d_ws, size_t ws_size,
                              hipStream_t stream) {
  const float* x     = (const float*)d_in[0];
  const int*   neigh = (const int*)d_in[1];
  const float* w     = (const float*)d_in[2];
  const float* gamma = (const float*)d_in[3];
  const float* beta  = (const float*)d_in[4];
  float* out = (float*)d_out;

  float* stats = (float*)d_ws;                                    // 512 B
  unsigned short* bfrag = (unsigned short*)((char*)d_ws + 1024);  // 32 KB
  unsigned short* obf = (unsigned short*)((char*)d_ws + 65536);   // 32 MB

  const bool bf16path =
      ws_size >= (size_t)65536 + (size_t)N_OUT_ROWS * 64 * 2;

  k_prep<<<8, 256, 0, stream>>>(w, bfrag, stats);
  if (bf16path) {
    k_gemm<true><<<NBLK, 256, 0, stream>>>(x, neigh, bfrag, nullptr, obf, stats);
    k_bn<true><<<2048, 256, 0, stream>>>(out, obf, stats, gamma, beta);
  } else {
    k_gemm<false><<<NBLK, 256, 0, stream>>>(x, neigh, bfrag, out, nullptr, stats);
    k_bn<false><<<2048, 256, 0, stream>>>(out, nullptr, stats, gamma, beta);
  }
}